// Round 1
// baseline (498.549 us; speedup 1.0000x reference)
//
#include <hip/hip_runtime.h>
#include <hip/hip_bf16.h>

using bf16_t = __bf16;
using bf16x8 = __attribute__((ext_vector_type(8))) __bf16;
using bf16x4 = __attribute__((ext_vector_type(4))) __bf16;
using f32x4  = __attribute__((ext_vector_type(4))) float;

#define S_  2048
#define D_  1024

typedef __attribute__((address_space(1))) unsigned int glb_u32;
typedef __attribute__((address_space(3))) unsigned int lds_u32;

// async global->LDS, 16B per lane. LDS dest must be wave-uniform base + lane*16.
__device__ __forceinline__ void async_cp16(const void* g, void* lds) {
    __builtin_amdgcn_global_load_lds(
        (glb_u32*)(unsigned long long)g,
        (lds_u32*)(unsigned int)(unsigned long long)lds,
        16, 0, 0);
}

// ---------------- f32 -> bf16 cast (vectorized) ----------------
__global__ __launch_bounds__(256) void cast_f32_bf16(const float* __restrict__ s,
                                                     bf16_t* __restrict__ d, int n4) {
    int i = blockIdx.x * 256 + threadIdx.x;
    if (i >= n4) return;
    float4 f = reinterpret_cast<const float4*>(s)[i];
    bf16x4 o;
    o[0] = (bf16_t)f.x; o[1] = (bf16_t)f.y; o[2] = (bf16_t)f.z; o[3] = (bf16_t)f.w;
    reinterpret_cast<bf16x4*>(d)[i] = o;
}

// ---------------- GEMM: C[M x 1024] = A[M x 1024] * Bt[1024 x 1024]^T ----------------
// m97 structure: 128x128 tile, BK=32, global_load_lds staging, 16x16x32 bf16 MFMA.
// grid = (N/128=8, M/128). block = 256 (4 waves, 2x2 of 64x64).
template <int F32OUT>
__global__ __launch_bounds__(256) void gemm_bt(const bf16_t* __restrict__ A,
                                               const bf16_t* __restrict__ Bt,
                                               void* __restrict__ Cv) {
    __shared__ bf16_t As[128 * 32];
    __shared__ bf16_t Bs[128 * 32];
    const int K = 1024;
    int tid  = threadIdx.x;
    int lane = tid & 63;
    int w    = tid >> 6;
    int l15  = lane & 15, quad = lane >> 4;
    int m0 = blockIdx.y * 128, n0 = blockIdx.x * 128;
    int wm = (w >> 1) * 64, wn = (w & 1) * 64;

    const bf16_t* Ag = A  + (size_t)(m0 + (tid >> 2)) * K + (tid & 3) * 8;
    const bf16_t* Bg = Bt + (size_t)(n0 + (tid >> 2)) * K + (tid & 3) * 8;
    bf16_t* Asw = As + tid * 8;
    bf16_t* Bsw = Bs + tid * 8;

    f32x4 acc[4][4] = {};

    for (int k0 = 0; k0 < K; k0 += 32) {
        __syncthreads();
        async_cp16(Ag + k0,                    Asw);
        async_cp16(Ag + k0 + (size_t)64 * K,   Asw + 2048);
        async_cp16(Bg + k0,                    Bsw);
        async_cp16(Bg + k0 + (size_t)64 * K,   Bsw + 2048);
        __syncthreads();
        bf16x8 af[4], bfr[4];
#pragma unroll
        for (int t = 0; t < 4; t++) {
            af[t]  = *reinterpret_cast<const bf16x8*>(&As[(wm + t * 16 + l15) * 32 + quad * 8]);
            bfr[t] = *reinterpret_cast<const bf16x8*>(&Bs[(wn + t * 16 + l15) * 32 + quad * 8]);
        }
#pragma unroll
        for (int mt = 0; mt < 4; mt++)
#pragma unroll
            for (int nt = 0; nt < 4; nt++)
                acc[mt][nt] = __builtin_amdgcn_mfma_f32_16x16x32_bf16(af[mt], bfr[nt], acc[mt][nt], 0, 0, 0);
    }

#pragma unroll
    for (int mt = 0; mt < 4; mt++)
#pragma unroll
        for (int nt = 0; nt < 4; nt++)
#pragma unroll
            for (int r = 0; r < 4; r++) {
                int m = m0 + wm + mt * 16 + quad * 4 + r;
                int n = n0 + wn + nt * 16 + l15;
                size_t idx = (size_t)m * 1024 + n;
                if (F32OUT) reinterpret_cast<float*>(Cv)[idx] = acc[mt][nt][r];
                else        reinterpret_cast<bf16_t*>(Cv)[idx] = (bf16_t)acc[mt][nt][r];
            }
}

// ---------------- fused masked attention (flash-style, per (b,h,qblock)) ----------------
// grid = (B*H=64, S/64=32), block = 256. Each wave owns 16 Q rows.
__global__ __launch_bounds__(256) void attn_fused(const bf16_t* __restrict__ Qp,
                                                  const bf16_t* __restrict__ Kp,
                                                  const bf16_t* __restrict__ Vp,
                                                  const int* __restrict__ vlen_p,
                                                  bf16_t* __restrict__ Out) {
    __shared__ bf16_t Qs[64 * 72];   // stride 72 keeps 16B align + breaks bank conflicts
    __shared__ bf16_t Ks[64 * 72];
    __shared__ bf16_t Vs[64 * 66];   // stride 66 -> conflict-free u16 column gathers
    __shared__ bf16_t Ps[64 * 72];   // P round-trip: C-layout -> A-layout

    int tid  = threadIdx.x;
    int lane = tid & 63, w = tid >> 6;
    int l15  = lane & 15, quad = lane >> 4;
    int bh = blockIdx.x;
    int b = bh >> 4, h = bh & 15;
    int qblk = blockIdx.y;
    int vlen = vlen_p[b];
    int nkb  = (vlen + 63) >> 6;     // masked-out blocks contribute exactly 0 -> skip

    const size_t rowQ0 = (size_t)(b * S_ + qblk * 64);

#pragma unroll
    for (int i = 0; i < 2; i++) {
        int linear = i * 256 + tid;
        int row = linear >> 3, c8 = linear & 7;
        uint4 val = *reinterpret_cast<const uint4*>(&Qp[(rowQ0 + row) * D_ + h * 64 + c8 * 8]);
        *reinterpret_cast<uint4*>(&Qs[row * 72 + c8 * 8]) = val;
    }
    __syncthreads();

    bf16x8 qf[2];
#pragma unroll
    for (int kk = 0; kk < 2; kk++)
        qf[kk] = *reinterpret_cast<const bf16x8*>(&Qs[(w * 16 + l15) * 72 + kk * 32 + quad * 8]);

    f32x4 o[4] = {};
    float m_st[4], l_st[4];
#pragma unroll
    for (int r = 0; r < 4; r++) { m_st[r] = -1e30f; l_st[r] = 0.f; }

    for (int kb = 0; kb < nkb; kb++) {
        __syncthreads();   // previous iteration's LDS reads complete
        const size_t rowK0 = (size_t)(b * S_ + kb * 64);
#pragma unroll
        for (int i = 0; i < 2; i++) {
            int linear = i * 256 + tid;
            int row = linear >> 3, c8 = linear & 7;
            uint4 kv = *reinterpret_cast<const uint4*>(&Kp[(rowK0 + row) * D_ + h * 64 + c8 * 8]);
            *reinterpret_cast<uint4*>(&Ks[row * 72 + c8 * 8]) = kv;
            uint4 vv = *reinterpret_cast<const uint4*>(&Vp[(rowK0 + row) * D_ + h * 64 + c8 * 8]);
            unsigned int* vp = reinterpret_cast<unsigned int*>(&Vs[row * 66 + c8 * 8]);
            vp[0] = vv.x; vp[1] = vv.y; vp[2] = vv.z; vp[3] = vv.w;
        }
        __syncthreads();

        // S = Q K^T (both operands k-contiguous: BT pattern)
        f32x4 sc[4] = {};
#pragma unroll
        for (int nt = 0; nt < 4; nt++)
#pragma unroll
            for (int kk = 0; kk < 2; kk++) {
                bf16x8 kf = *reinterpret_cast<const bf16x8*>(&Ks[(nt * 16 + l15) * 72 + kk * 32 + quad * 8]);
                sc[nt] = __builtin_amdgcn_mfma_f32_16x16x32_bf16(qf[kk], kf, sc[nt], 0, 0, 0);
            }

        // online softmax; lane holds rows quad*4+r, col l15+16*nt
#pragma unroll
        for (int r = 0; r < 4; r++) {
            float sval[4];
            float mx = -1e30f;
#pragma unroll
            for (int nt = 0; nt < 4; nt++) {
                int col = kb * 64 + nt * 16 + l15;
                float sv = (col < vlen) ? sc[nt][r] * 0.125f : -1e30f;
                sval[nt] = sv;
                mx = fmaxf(mx, sv);
            }
            mx = fmaxf(mx, __shfl_xor(mx, 1));
            mx = fmaxf(mx, __shfl_xor(mx, 2));
            mx = fmaxf(mx, __shfl_xor(mx, 4));
            mx = fmaxf(mx, __shfl_xor(mx, 8));
            float mnew  = fmaxf(m_st[r], mx);
            float alpha = __expf(m_st[r] - mnew);
            m_st[r] = mnew;
            float rs = 0.f;
#pragma unroll
            for (int nt = 0; nt < 4; nt++) {
                float p = __expf(sval[nt] - mnew);
                rs += p;
                Ps[(w * 16 + quad * 4 + r) * 72 + nt * 16 + l15] = (bf16_t)p;
            }
            rs += __shfl_xor(rs, 1);
            rs += __shfl_xor(rs, 2);
            rs += __shfl_xor(rs, 4);
            rs += __shfl_xor(rs, 8);
            l_st[r] = l_st[r] * alpha + rs;
#pragma unroll
            for (int dt = 0; dt < 4; dt++) o[dt][r] *= alpha;
        }

        // O += P V  (P from LDS in A-layout; V columns via u16 gathers)
        bf16x8 pf0 = *reinterpret_cast<const bf16x8*>(&Ps[(w * 16 + l15) * 72 + quad * 8]);
        bf16x8 pf1 = *reinterpret_cast<const bf16x8*>(&Ps[(w * 16 + l15) * 72 + 32 + quad * 8]);
#pragma unroll
        for (int dt = 0; dt < 4; dt++)
#pragma unroll
            for (int kk = 0; kk < 2; kk++) {
                bf16x8 vf;
#pragma unroll
                for (int j = 0; j < 8; j++)
                    vf[j] = Vs[(kk * 32 + quad * 8 + j) * 66 + dt * 16 + l15];
                o[dt] = __builtin_amdgcn_mfma_f32_16x16x32_bf16(kk ? pf1 : pf0, vf, o[dt], 0, 0, 0);
            }
    }

#pragma unroll
    for (int r = 0; r < 4; r++) {
        float inv = 1.0f / l_st[r];
        size_t orow = (rowQ0 + w * 16 + quad * 4 + r) * D_ + h * 64;
#pragma unroll
        for (int dt = 0; dt < 4; dt++)
            Out[orow + dt * 16 + l15] = (bf16_t)(o[dt][r] * inv);
    }
}

extern "C" void kernel_launch(void* const* d_in, const int* in_sizes, int n_in,
                              void* d_out, int out_size, void* d_ws, size_t ws_size,
                              hipStream_t stream) {
    const float* q  = (const float*)d_in[0];
    const float* k  = (const float*)d_in[1];
    const float* v  = (const float*)d_in[2];
    const int*   vl = (const int*)d_in[3];
    const float* Wq = (const float*)d_in[4];
    const float* Wk = (const float*)d_in[5];
    const float* Wv = (const float*)d_in[6];
    const float* Wo = (const float*)d_in[7];
    float* out = (float*)d_out;

    bf16_t* ws = (bf16_t*)d_ws;
    const size_t SD = (size_t)8192 * 1024;   // 8,388,608 elems
    const size_t WW = (size_t)1024 * 1024;
    bf16_t* tmp = ws;              // input-cast buffer, later attn output
    bf16_t* Qp  = ws + SD;
    bf16_t* Kp  = ws + 2 * SD;
    bf16_t* Vp  = ws + 3 * SD;
    bf16_t* Wqb = ws + 4 * SD;
    bf16_t* Wkb = Wqb + WW;
    bf16_t* Wvb = Wqb + 2 * WW;
    bf16_t* Wob = Wqb + 3 * WW;
    // total ws use: (4*SD + 4*WW)*2 = 75.5 MB

    dim3 blk(256);
    dim3 gg(8, 64);   // N/128, M/128

    cast_f32_bf16<<<dim3(1024), blk, 0, stream>>>(Wq, Wqb, 262144);
    cast_f32_bf16<<<dim3(1024), blk, 0, stream>>>(Wk, Wkb, 262144);
    cast_f32_bf16<<<dim3(1024), blk, 0, stream>>>(Wv, Wvb, 262144);
    cast_f32_bf16<<<dim3(1024), blk, 0, stream>>>(Wo, Wob, 262144);

    cast_f32_bf16<<<dim3(8192), blk, 0, stream>>>(q, tmp, 2097152);
    gemm_bt<0><<<gg, blk, 0, stream>>>(tmp, Wqb, Qp);
    cast_f32_bf16<<<dim3(8192), blk, 0, stream>>>(k, tmp, 2097152);
    gemm_bt<0><<<gg, blk, 0, stream>>>(tmp, Wkb, Kp);
    cast_f32_bf16<<<dim3(8192), blk, 0, stream>>>(v, tmp, 2097152);
    gemm_bt<0><<<gg, blk, 0, stream>>>(tmp, Wvb, Vp);

    attn_fused<<<dim3(64, 32), blk, 0, stream>>>(Qp, Kp, Vp, vl, tmp);
    gemm_bt<1><<<gg, blk, 0, stream>>>(tmp, Wob, out);
}

// Round 2
// 484.927 us; speedup vs baseline: 1.0281x; 1.0281x over previous
//
#include <hip/hip_runtime.h>
#include <hip/hip_bf16.h>

using bf16_t = __bf16;
using bf16x8 = __attribute__((ext_vector_type(8))) __bf16;
using bf16x4 = __attribute__((ext_vector_type(4))) __bf16;
using f32x4  = __attribute__((ext_vector_type(4))) float;

#define S_  2048
#define D_  1024

typedef __attribute__((address_space(1))) unsigned int glb_u32;
typedef __attribute__((address_space(3))) unsigned int lds_u32;

// async global->LDS, 16B per lane. LDS dest must be wave-uniform base + lane*16.
__device__ __forceinline__ void async_cp16(const void* g, void* lds) {
    __builtin_amdgcn_global_load_lds(
        (glb_u32*)(unsigned long long)g,
        (lds_u32*)(unsigned int)(unsigned long long)lds,
        16, 0, 0);
}

// ---------------- f32 -> bf16 cast (vectorized) ----------------
__global__ __launch_bounds__(256) void cast_f32_bf16(const float* __restrict__ s,
                                                     bf16_t* __restrict__ d, int n4) {
    int i = blockIdx.x * 256 + threadIdx.x;
    if (i >= n4) return;
    float4 f = reinterpret_cast<const float4*>(s)[i];
    bf16x4 o;
    o[0] = (bf16_t)f.x; o[1] = (bf16_t)f.y; o[2] = (bf16_t)f.z; o[3] = (bf16_t)f.w;
    reinterpret_cast<bf16x4*>(d)[i] = o;
}

// ---------------- GEMM: C[M x 1024] = A[M x 1024] * Bt[1024 x 1024]^T ----------------
template <int F32OUT>
__global__ __launch_bounds__(256) void gemm_bt(const bf16_t* __restrict__ A,
                                               const bf16_t* __restrict__ Bt,
                                               void* __restrict__ Cv) {
    __shared__ bf16_t As[128 * 32];
    __shared__ bf16_t Bs[128 * 32];
    const int K = 1024;
    int tid  = threadIdx.x;
    int lane = tid & 63;
    int w    = tid >> 6;
    int l15  = lane & 15, quad = lane >> 4;
    int m0 = blockIdx.y * 128, n0 = blockIdx.x * 128;
    int wm = (w >> 1) * 64, wn = (w & 1) * 64;

    const bf16_t* Ag = A  + (size_t)(m0 + (tid >> 2)) * K + (tid & 3) * 8;
    const bf16_t* Bg = Bt + (size_t)(n0 + (tid >> 2)) * K + (tid & 3) * 8;
    bf16_t* Asw = As + tid * 8;
    bf16_t* Bsw = Bs + tid * 8;

    f32x4 acc[4][4] = {};

    for (int k0 = 0; k0 < K; k0 += 32) {
        __syncthreads();
        async_cp16(Ag + k0,                    Asw);
        async_cp16(Ag + k0 + (size_t)64 * K,   Asw + 2048);
        async_cp16(Bg + k0,                    Bsw);
        async_cp16(Bg + k0 + (size_t)64 * K,   Bsw + 2048);
        __syncthreads();
        bf16x8 af[4], bfr[4];
#pragma unroll
        for (int t = 0; t < 4; t++) {
            af[t]  = *reinterpret_cast<const bf16x8*>(&As[(wm + t * 16 + l15) * 32 + quad * 8]);
            bfr[t] = *reinterpret_cast<const bf16x8*>(&Bs[(wn + t * 16 + l15) * 32 + quad * 8]);
        }
#pragma unroll
        for (int mt = 0; mt < 4; mt++)
#pragma unroll
            for (int nt = 0; nt < 4; nt++)
                acc[mt][nt] = __builtin_amdgcn_mfma_f32_16x16x32_bf16(af[mt], bfr[nt], acc[mt][nt], 0, 0, 0);
    }

#pragma unroll
    for (int mt = 0; mt < 4; mt++)
#pragma unroll
        for (int nt = 0; nt < 4; nt++)
#pragma unroll
            for (int r = 0; r < 4; r++) {
                int m = m0 + wm + mt * 16 + quad * 4 + r;
                int n = n0 + wn + nt * 16 + l15;
                size_t idx = (size_t)m * 1024 + n;
                if (F32OUT) reinterpret_cast<float*>(Cv)[idx] = acc[mt][nt][r];
                else        reinterpret_cast<bf16_t*>(Cv)[idx] = (bf16_t)acc[mt][nt][r];
            }
}

// ---------------- V transpose: Vp (B*S, D) -> Vt[(b*16+h)*64 + d][s] ----------------
// grid = (64 bh, 32 sblk), block 256. Coalesced read + coalesced write via LDS tile.
__global__ __launch_bounds__(256) void transpose_v(const bf16_t* __restrict__ Vp,
                                                   bf16_t* __restrict__ Vt) {
    __shared__ bf16_t T[64 * 72];
    int tid = threadIdx.x;
    int bh = blockIdx.x, b = bh >> 4, h = bh & 15;
    int sb = blockIdx.y;
#pragma unroll
    for (int i = 0; i < 2; i++) {
        int linear = i * 256 + tid;
        int s = linear >> 3, c8 = linear & 7;
        *reinterpret_cast<uint4*>(&T[s * 72 + c8 * 8]) =
            *reinterpret_cast<const uint4*>(&Vp[(size_t)(b * S_ + sb * 64 + s) * D_ + h * 64 + c8 * 8]);
    }
    __syncthreads();
#pragma unroll
    for (int i = 0; i < 2; i++) {
        int linear = i * 256 + tid;
        int d = linear >> 3, sg = linear & 7;
        bf16x8 v;
#pragma unroll
        for (int j = 0; j < 8; j++) v[j] = T[(sg * 8 + j) * 72 + d];
        *reinterpret_cast<bf16x8*>(&Vt[((size_t)bh * 64 + d) * S_ + sb * 64 + sg * 8]) = v;
    }
}

// ---------------- fused masked attention (flash-style) ----------------
// grid = (B*H=64, S/64=32), block = 256 (4 waves, each owns 16 q rows).
// LDS layouts chunked [kk][row][32] so global_load_lds staging is legal (no pad)
// and fragment reads are contiguous b128.
__global__ __launch_bounds__(256) void attn_fused(const bf16_t* __restrict__ Qp,
                                                  const bf16_t* __restrict__ Kp,
                                                  const bf16_t* __restrict__ Vt,
                                                  const int* __restrict__ vlen_p,
                                                  bf16_t* __restrict__ Out) {
    __shared__ bf16_t Qs[2 * 64 * 32];
    __shared__ bf16_t Ks[2 * 64 * 32];
    __shared__ bf16_t Vs[2 * 64 * 32];
    __shared__ bf16_t Ps[64 * 72];

    int tid  = threadIdx.x;
    int lane = tid & 63, w = tid >> 6;
    int l15  = lane & 15, quad = lane >> 4;
    int bh = blockIdx.x, b = bh >> 4, h = bh & 15;
    int qblk = blockIdx.y;
    int vlen = vlen_p[b];
    int nkb  = (vlen + 63) >> 6;
    const float cs = 0.18033688f;   // (1/8) * log2(e): softmax tracked in exp2 domain

    // ---- stage Q once (async, chunked) ----
    {
        const bf16_t* Qg = Qp + (size_t)(b * S_ + qblk * 64) * D_ + h * 64;
#pragma unroll
        for (int i = 0; i < 2; i++) {
            int linear = i * 256 + tid;
            int kk = linear >> 8, row = (linear >> 2) & 63, sub = linear & 3;
            async_cp16(Qg + (size_t)row * D_ + kk * 32 + sub * 8, Qs + linear * 8);
        }
    }
    __syncthreads();
    bf16x8 qf[2];
    qf[0] = *reinterpret_cast<const bf16x8*>(&Qs[(w * 16 + l15) * 32 + quad * 8]);
    qf[1] = *reinterpret_cast<const bf16x8*>(&Qs[2048 + (w * 16 + l15) * 32 + quad * 8]);

    f32x4 o[4] = {};
    float m_st[4], l_st[4];
#pragma unroll
    for (int r = 0; r < 4; r++) { m_st[r] = -1e30f; l_st[r] = 0.f; }

    const bf16_t* Kg = Kp + (size_t)b * S_ * D_ + h * 64;
    const bf16_t* Vg = Vt + (size_t)bh * 64 * S_;

    for (int kb = 0; kb < nkb; kb++) {
        __syncthreads();   // prior iteration's LDS reads complete before overwrite
#pragma unroll
        for (int i = 0; i < 2; i++) {
            int linear = i * 256 + tid;
            int kk = linear >> 8, row = (linear >> 2) & 63, sub = linear & 3;
            async_cp16(Kg + (size_t)(kb * 64 + row) * D_ + kk * 32 + sub * 8, Ks + linear * 8);
            async_cp16(Vg + (size_t)row * S_ + kb * 64 + kk * 32 + sub * 8,   Vs + linear * 8);
        }
        __syncthreads();

        // S = Q K^T
        f32x4 sc[4] = {};
#pragma unroll
        for (int nt = 0; nt < 4; nt++)
#pragma unroll
            for (int kk = 0; kk < 2; kk++) {
                bf16x8 kf = *reinterpret_cast<const bf16x8*>(&Ks[kk * 2048 + (nt * 16 + l15) * 32 + quad * 8]);
                sc[nt] = __builtin_amdgcn_mfma_f32_16x16x32_bf16(qf[kk], kf, sc[nt], 0, 0, 0);
            }

        // online softmax (exp2 domain); only final partial block pays the mask
        bool partial = (vlen & 63) && (kb == nkb - 1);
#pragma unroll
        for (int r = 0; r < 4; r++) {
            float sv[4];
#pragma unroll
            for (int nt = 0; nt < 4; nt++) sv[nt] = sc[nt][r];
            if (partial) {
#pragma unroll
                for (int nt = 0; nt < 4; nt++)
                    if (kb * 64 + nt * 16 + l15 >= vlen) sv[nt] = -1e30f;
            }
            float mx = fmaxf(fmaxf(sv[0], sv[1]), fmaxf(sv[2], sv[3]));
            mx = fmaxf(mx, __shfl_xor(mx, 1));
            mx = fmaxf(mx, __shfl_xor(mx, 2));
            mx = fmaxf(mx, __shfl_xor(mx, 4));
            mx = fmaxf(mx, __shfl_xor(mx, 8));
            float mnew  = fmaxf(m_st[r], mx * cs);
            float alpha = __builtin_exp2f(m_st[r] - mnew);
            m_st[r] = mnew;
            float rs = 0.f;
#pragma unroll
            for (int nt = 0; nt < 4; nt++) {
                float p = __builtin_exp2f(fmaf(sv[nt], cs, -mnew));
                rs += p;
                Ps[(w * 16 + quad * 4 + r) * 72 + nt * 16 + l15] = (bf16_t)p;
            }
            rs += __shfl_xor(rs, 1);
            rs += __shfl_xor(rs, 2);
            rs += __shfl_xor(rs, 4);
            rs += __shfl_xor(rs, 8);
            l_st[r] = l_st[r] * alpha + rs;
#pragma unroll
            for (int dt = 0; dt < 4; dt++) o[dt][r] *= alpha;
        }

        // O += P V : P via LDS roundtrip (A-layout), V fragments contiguous b128
        bf16x8 pf[2];
        pf[0] = *reinterpret_cast<const bf16x8*>(&Ps[(w * 16 + l15) * 72 + quad * 8]);
        pf[1] = *reinterpret_cast<const bf16x8*>(&Ps[(w * 16 + l15) * 72 + 32 + quad * 8]);
#pragma unroll
        for (int dt = 0; dt < 4; dt++)
#pragma unroll
            for (int kk = 0; kk < 2; kk++) {
                bf16x8 vf = *reinterpret_cast<const bf16x8*>(&Vs[kk * 2048 + (dt * 16 + l15) * 32 + quad * 8]);
                o[dt] = __builtin_amdgcn_mfma_f32_16x16x32_bf16(pf[kk], vf, o[dt], 0, 0, 0);
            }
    }

#pragma unroll
    for (int r = 0; r < 4; r++) {
        float inv = 1.0f / l_st[r];
        size_t orow = ((size_t)(b * S_ + qblk * 64) + w * 16 + quad * 4 + r) * D_ + h * 64;
#pragma unroll
        for (int dt = 0; dt < 4; dt++)
            Out[orow + dt * 16 + l15] = (bf16_t)(o[dt][r] * inv);
    }
}

extern "C" void kernel_launch(void* const* d_in, const int* in_sizes, int n_in,
                              void* d_out, int out_size, void* d_ws, size_t ws_size,
                              hipStream_t stream) {
    const float* q  = (const float*)d_in[0];
    const float* k  = (const float*)d_in[1];
    const float* v  = (const float*)d_in[2];
    const int*   vl = (const int*)d_in[3];
    const float* Wq = (const float*)d_in[4];
    const float* Wk = (const float*)d_in[5];
    const float* Wv = (const float*)d_in[6];
    const float* Wo = (const float*)d_in[7];
    float* out = (float*)d_out;

    bf16_t* ws = (bf16_t*)d_ws;
    const size_t SD = (size_t)8192 * 1024;
    const size_t WW = (size_t)1024 * 1024;
    bf16_t* tmp = ws;              // input-cast buffer, later attn output
    bf16_t* Qp  = ws + SD;
    bf16_t* Kp  = ws + 2 * SD;
    bf16_t* Vp  = ws + 3 * SD;
    bf16_t* Wqb = ws + 4 * SD;
    bf16_t* Wkb = Wqb + WW;
    bf16_t* Wvb = Wqb + 2 * WW;
    bf16_t* Wob = Wqb + 3 * WW;
    bf16_t* Vt  = Wqb + 4 * WW;    // (B*H*64, S) transposed V
    // total ws use: (5*SD + 4*WW)*2 = 88.1 MB

    dim3 blk(256);
    dim3 gg(8, 64);   // N/128, M/128

    cast_f32_bf16<<<dim3(1024), blk, 0, stream>>>(Wq, Wqb, 262144);
    cast_f32_bf16<<<dim3(1024), blk, 0, stream>>>(Wk, Wkb, 262144);
    cast_f32_bf16<<<dim3(1024), blk, 0, stream>>>(Wv, Wvb, 262144);
    cast_f32_bf16<<<dim3(1024), blk, 0, stream>>>(Wo, Wob, 262144);

    cast_f32_bf16<<<dim3(8192), blk, 0, stream>>>(q, tmp, 2097152);
    gemm_bt<0><<<gg, blk, 0, stream>>>(tmp, Wqb, Qp);
    cast_f32_bf16<<<dim3(8192), blk, 0, stream>>>(k, tmp, 2097152);
    gemm_bt<0><<<gg, blk, 0, stream>>>(tmp, Wkb, Kp);
    cast_f32_bf16<<<dim3(8192), blk, 0, stream>>>(v, tmp, 2097152);
    gemm_bt<0><<<gg, blk, 0, stream>>>(tmp, Wvb, Vp);

    transpose_v<<<dim3(64, 32), blk, 0, stream>>>(Vp, Vt);
    attn_fused<<<dim3(64, 32), blk, 0, stream>>>(Qp, Kp, Vt, vl, tmp);
    gemm_bt<1><<<gg, blk, 0, stream>>>(tmp, Wob, out);
}

// Round 3
// 390.308 us; speedup vs baseline: 1.2773x; 1.2424x over previous
//
#include <hip/hip_runtime.h>
#include <hip/hip_bf16.h>

using bf16_t = __bf16;
using bf16x8 = __attribute__((ext_vector_type(8))) __bf16;
using bf16x4 = __attribute__((ext_vector_type(4))) __bf16;
using bf16x2 = __attribute__((ext_vector_type(2))) __bf16;
using f32x4  = __attribute__((ext_vector_type(4))) float;

#define S_  2048
#define D_  1024

typedef __attribute__((address_space(1))) unsigned int glb_u32;
typedef __attribute__((address_space(3))) unsigned int lds_u32;

__device__ __forceinline__ void async_cp16(const void* g, void* lds) {
    __builtin_amdgcn_global_load_lds(
        (glb_u32*)(unsigned long long)g,
        (lds_u32*)(unsigned int)(unsigned long long)lds,
        16, 0, 0);
}

// ---------------- f32 -> bf16 cast ----------------
__global__ __launch_bounds__(256) void cast_f32_bf16(const float* __restrict__ s,
                                                     bf16_t* __restrict__ d, int n4) {
    int i = blockIdx.x * 256 + threadIdx.x;
    if (i >= n4) return;
    float4 f = reinterpret_cast<const float4*>(s)[i];
    bf16x4 o;
    o[0] = (bf16_t)f.x; o[1] = (bf16_t)f.y; o[2] = (bf16_t)f.z; o[3] = (bf16_t)f.w;
    reinterpret_cast<bf16x4*>(d)[i] = o;
}

// 4 weight matrices in one launch (blockIdx.y selects)
__global__ __launch_bounds__(256) void cast4_f32_bf16(const float* __restrict__ a, const float* __restrict__ b,
                                                      const float* __restrict__ c, const float* __restrict__ dd,
                                                      bf16_t* __restrict__ oa, bf16_t* __restrict__ ob,
                                                      bf16_t* __restrict__ oc, bf16_t* __restrict__ od, int n4) {
    int i = blockIdx.x * 256 + threadIdx.x;
    if (i >= n4) return;
    const float* s; bf16_t* d;
    int w = blockIdx.y;
    if      (w == 0) { s = a;  d = oa; }
    else if (w == 1) { s = b;  d = ob; }
    else if (w == 2) { s = c;  d = oc; }
    else             { s = dd; d = od; }
    float4 f = reinterpret_cast<const float4*>(s)[i];
    bf16x4 o;
    o[0] = (bf16_t)f.x; o[1] = (bf16_t)f.y; o[2] = (bf16_t)f.z; o[3] = (bf16_t)f.w;
    reinterpret_cast<bf16x4*>(d)[i] = o;
}

// ---------------- GEMM: C[M x 1024] = A[M x 1024] * Bt[1024 x 1024]^T ----------------
template <int F32OUT>
__global__ __launch_bounds__(256) void gemm_bt(const bf16_t* __restrict__ A,
                                               const bf16_t* __restrict__ Bt,
                                               void* __restrict__ Cv) {
    __shared__ bf16_t As[128 * 32];
    __shared__ bf16_t Bs[128 * 32];
    const int K = 1024;
    int tid  = threadIdx.x;
    int lane = tid & 63;
    int w    = tid >> 6;
    int l15  = lane & 15, quad = lane >> 4;
    int m0 = blockIdx.y * 128, n0 = blockIdx.x * 128;
    int wm = (w >> 1) * 64, wn = (w & 1) * 64;

    const bf16_t* Ag = A  + (size_t)(m0 + (tid >> 2)) * K + (tid & 3) * 8;
    const bf16_t* Bg = Bt + (size_t)(n0 + (tid >> 2)) * K + (tid & 3) * 8;
    bf16_t* Asw = As + tid * 8;
    bf16_t* Bsw = Bs + tid * 8;

    f32x4 acc[4][4] = {};

    for (int k0 = 0; k0 < K; k0 += 32) {
        __syncthreads();
        async_cp16(Ag + k0,                    Asw);
        async_cp16(Ag + k0 + (size_t)64 * K,   Asw + 2048);
        async_cp16(Bg + k0,                    Bsw);
        async_cp16(Bg + k0 + (size_t)64 * K,   Bsw + 2048);
        __syncthreads();
        bf16x8 af[4], bfr[4];
#pragma unroll
        for (int t = 0; t < 4; t++) {
            af[t]  = *reinterpret_cast<const bf16x8*>(&As[(wm + t * 16 + l15) * 32 + quad * 8]);
            bfr[t] = *reinterpret_cast<const bf16x8*>(&Bs[(wn + t * 16 + l15) * 32 + quad * 8]);
        }
#pragma unroll
        for (int mt = 0; mt < 4; mt++)
#pragma unroll
            for (int nt = 0; nt < 4; nt++)
                acc[mt][nt] = __builtin_amdgcn_mfma_f32_16x16x32_bf16(af[mt], bfr[nt], acc[mt][nt], 0, 0, 0);
    }

#pragma unroll
    for (int mt = 0; mt < 4; mt++)
#pragma unroll
        for (int nt = 0; nt < 4; nt++)
#pragma unroll
            for (int r = 0; r < 4; r++) {
                int m = m0 + wm + mt * 16 + quad * 4 + r;
                int n = n0 + wn + nt * 16 + l15;
                size_t idx = (size_t)m * 1024 + n;
                if (F32OUT) reinterpret_cast<float*>(Cv)[idx] = acc[mt][nt][r];
                else        reinterpret_cast<bf16_t*>(Cv)[idx] = (bf16_t)acc[mt][nt][r];
            }
}

// ---------------- V transpose: Vp (B*S, D) -> Vt[(b*16+h)*64 + d][s] ----------------
__global__ __launch_bounds__(256) void transpose_v(const bf16_t* __restrict__ Vp,
                                                   bf16_t* __restrict__ Vt) {
    __shared__ bf16_t T[64 * 72];
    int tid = threadIdx.x;
    int bh = blockIdx.x, b = bh >> 4, h = bh & 15;
    int sb = blockIdx.y;
#pragma unroll
    for (int i = 0; i < 2; i++) {
        int linear = i * 256 + tid;
        int s = linear >> 3, c8 = linear & 7;
        *reinterpret_cast<uint4*>(&T[s * 72 + c8 * 8]) =
            *reinterpret_cast<const uint4*>(&Vp[(size_t)(b * S_ + sb * 64 + s) * D_ + h * 64 + c8 * 8]);
    }
    __syncthreads();
#pragma unroll
    for (int i = 0; i < 2; i++) {
        int linear = i * 256 + tid;
        int d = linear >> 3, sg = linear & 7;
        bf16x8 v;
#pragma unroll
        for (int j = 0; j < 8; j++) v[j] = T[(sg * 8 + j) * 72 + d];
        *reinterpret_cast<bf16x8*>(&Vt[((size_t)bh * 64 + d) * S_ + sb * 64 + sg * 8]) = v;
    }
}

// ---------------- fused masked attention ----------------
// Transposed-S formulation: St = K Q^T (C-layout: qrow=l15, kcol=quad*4+r) feeds
// PV as O^T = V^T P^T with P^T straight from registers — no P LDS round-trip.
// Max-free exp2 softmax (scores bounded ~|q||k|/1 << overflow) — no shuffles in loop.
// 2 Q-tiles per wave: WG covers 128 q rows; grid (B*H=64, S/128=16).
__global__ __launch_bounds__(256) void attn_fused(const bf16_t* __restrict__ Qp,
                                                  const bf16_t* __restrict__ Kp,
                                                  const bf16_t* __restrict__ Vt,
                                                  const int* __restrict__ vlen_p,
                                                  bf16_t* __restrict__ Out) {
    __shared__ bf16_t Qs[2 * 128 * 32];   // [kk][row][32]; reused as T[128][64] in epilogue
    __shared__ bf16_t Ks[2 * 64 * 32];    // [kk][row][32]
    __shared__ bf16_t Vs[64 * 72];        // [d][s] padded

    int tid  = threadIdx.x;
    int lane = tid & 63, w = tid >> 6;
    int l15  = lane & 15, quad = lane >> 4;
    int bh = blockIdx.x, b = bh >> 4, h = bh & 15;
    int qblk = blockIdx.y;
    int vlen = vlen_p[b];
    int nkb  = (vlen + 63) >> 6;
    const float cs = 0.18033688f;   // (1/8)*log2(e)

    const bf16_t* Qg = Qp + (size_t)(b * S_ + qblk * 128) * D_ + h * 64;
    const bf16_t* Kg = Kp + (size_t)b * S_ * D_ + h * 64;
    const bf16_t* Vg = Vt + (size_t)bh * 64 * S_;

    // stage Q (128 rows x 64d) async, chunked
#pragma unroll
    for (int j = 0; j < 4; j++) {
        int linear = j * 256 + tid;
        int kk = linear >> 9, row = (linear >> 2) & 127, sub = linear & 3;
        async_cp16(Qg + (size_t)row * D_ + kk * 32 + sub * 8, Qs + linear * 8);
    }
    __syncthreads();
    bf16x8 qf[2][2];
#pragma unroll
    for (int qt = 0; qt < 2; qt++)
#pragma unroll
        for (int kk = 0; kk < 2; kk++)
            qf[qt][kk] = *reinterpret_cast<const bf16x8*>(&Qs[kk * 4096 + (w * 32 + qt * 16 + l15) * 32 + quad * 8]);

    f32x4 o[2][4] = {};
    float l_st[2] = {0.f, 0.f};

    for (int kb = 0; kb < nkb; kb++) {
        __syncthreads();
#pragma unroll
        for (int j = 0; j < 2; j++) {
            int linear = j * 256 + tid;
            int kk = linear >> 8, row = (linear >> 2) & 63, sub = linear & 3;
            async_cp16(Kg + (size_t)(kb * 64 + row) * D_ + kk * 32 + sub * 8, Ks + linear * 8);
        }
#pragma unroll
        for (int j = 0; j < 2; j++) {
            int linear = j * 256 + tid;
            int row = linear >> 3, c8 = linear & 7;
            uint4 vv = *reinterpret_cast<const uint4*>(&Vg[(size_t)row * S_ + kb * 64 + c8 * 8]);
            *reinterpret_cast<uint4*>(&Vs[row * 72 + c8 * 8]) = vv;
        }
        __syncthreads();

        // St = K Q^T for both q-tiles, sharing K fragments
        f32x4 sc[2][4] = {};
#pragma unroll
        for (int nt = 0; nt < 4; nt++)
#pragma unroll
            for (int kk = 0; kk < 2; kk++) {
                bf16x8 kf = *reinterpret_cast<const bf16x8*>(&Ks[kk * 2048 + (nt * 16 + l15) * 32 + quad * 8]);
                sc[0][nt] = __builtin_amdgcn_mfma_f32_16x16x32_bf16(kf, qf[0][kk], sc[0][nt], 0, 0, 0);
                sc[1][nt] = __builtin_amdgcn_mfma_f32_16x16x32_bf16(kf, qf[1][kk], sc[1][nt], 0, 0, 0);
            }

        // max-free softmax: p = exp2(s*cs); per-lane l accumulation (reduced at end)
        bool partial = (vlen & 63) && (kb == nkb - 1);
        bf16x8 pf[2][2];   // [qt][np]: P^T B-fragments, k = quad*8 + (nt&1)*4 + r
        if (!partial) {
#pragma unroll
            for (int qt = 0; qt < 2; qt++) {
                float lacc = 0.f;
#pragma unroll
                for (int nt = 0; nt < 4; nt++)
#pragma unroll
                    for (int r = 0; r < 4; r++) {
                        float p = __builtin_exp2f(sc[qt][nt][r] * cs);
                        lacc += p;
                        pf[qt][nt >> 1][(nt & 1) * 4 + r] = (bf16_t)p;
                    }
                l_st[qt] += lacc;
            }
        } else {
#pragma unroll
            for (int qt = 0; qt < 2; qt++) {
                float lacc = 0.f;
#pragma unroll
                for (int nt = 0; nt < 4; nt++)
#pragma unroll
                    for (int r = 0; r < 4; r++) {
                        float p = __builtin_exp2f(sc[qt][nt][r] * cs);
                        if (kb * 64 + nt * 16 + quad * 4 + r >= vlen) p = 0.f;
                        lacc += p;
                        pf[qt][nt >> 1][(nt & 1) * 4 + r] = (bf16_t)p;
                    }
                l_st[qt] += lacc;
            }
        }

        // O^T += V^T P^T ; V^T A-fragments via two b64 reads, shared across q-tiles
#pragma unroll
        for (int np = 0; np < 2; np++)
#pragma unroll
            for (int dt = 0; dt < 4; dt++) {
                bf16x4 v0 = *reinterpret_cast<const bf16x4*>(&Vs[(dt * 16 + l15) * 72 + np * 32 + quad * 4]);
                bf16x4 v1 = *reinterpret_cast<const bf16x4*>(&Vs[(dt * 16 + l15) * 72 + np * 32 + 16 + quad * 4]);
                bf16x8 vf;
#pragma unroll
                for (int j = 0; j < 4; j++) { vf[j] = v0[j]; vf[4 + j] = v1[j]; }
                o[0][dt] = __builtin_amdgcn_mfma_f32_16x16x32_bf16(vf, pf[0][np], o[0][dt], 0, 0, 0);
                o[1][dt] = __builtin_amdgcn_mfma_f32_16x16x32_bf16(vf, pf[1][np], o[1][dt], 0, 0, 0);
            }
    }

    // finalize l (cross-quad reduce, once)
    float inv[2];
#pragma unroll
    for (int qt = 0; qt < 2; qt++) {
        float l = l_st[qt];
        l += __shfl_xor(l, 16);
        l += __shfl_xor(l, 32);
        inv[qt] = 1.0f / l;
    }

    // epilogue: O^T (d-major in regs) -> T (XOR-swizzled, reusing Qs) -> coalesced store
    __syncthreads();
    bf16_t* T = Qs;   // [128 rows][8 chunks of 8 bf16], chunk phys = logical ^ (row&7)
#pragma unroll
    for (int qt = 0; qt < 2; qt++) {
        int row = w * 32 + qt * 16 + l15;
#pragma unroll
        for (int dt = 0; dt < 4; dt++) {
            int phys = ((dt * 2 + (quad >> 1)) ^ (l15 & 7));
            int base = row * 64 + phys * 8 + (quad & 1) * 4;
            bf16x2 t0, t1;
            t0[0] = (bf16_t)(o[qt][dt][0] * inv[qt]);
            t0[1] = (bf16_t)(o[qt][dt][1] * inv[qt]);
            t1[0] = (bf16_t)(o[qt][dt][2] * inv[qt]);
            t1[1] = (bf16_t)(o[qt][dt][3] * inv[qt]);
            *reinterpret_cast<bf16x2*>(&T[base])     = t0;
            *reinterpret_cast<bf16x2*>(&T[base + 2]) = t1;
        }
    }
    __syncthreads();
    {
        int row = w * 32 + (lane >> 1);
        int ch  = lane & 1;
        size_t orow = ((size_t)(b * S_ + qblk * 128) + row) * D_ + h * 64 + ch * 32;
#pragma unroll
        for (int k = 0; k < 4; k++) {
            int phys = (ch * 4 + k) ^ (row & 7);
            bf16x8 frag = *reinterpret_cast<const bf16x8*>(&T[row * 64 + phys * 8]);
            *reinterpret_cast<bf16x8*>(&Out[orow + k * 8]) = frag;
        }
    }
}

extern "C" void kernel_launch(void* const* d_in, const int* in_sizes, int n_in,
                              void* d_out, int out_size, void* d_ws, size_t ws_size,
                              hipStream_t stream) {
    const float* q  = (const float*)d_in[0];
    const float* k  = (const float*)d_in[1];
    const float* v  = (const float*)d_in[2];
    const int*   vl = (const int*)d_in[3];
    const float* Wq = (const float*)d_in[4];
    const float* Wk = (const float*)d_in[5];
    const float* Wv = (const float*)d_in[6];
    const float* Wo = (const float*)d_in[7];
    float* out = (float*)d_out;

    bf16_t* ws = (bf16_t*)d_ws;
    const size_t SD = (size_t)8192 * 1024;
    const size_t WW = (size_t)1024 * 1024;
    bf16_t* tmp = ws;              // input-cast buffer, later attn output
    bf16_t* Qp  = ws + SD;
    bf16_t* Kp  = ws + 2 * SD;
    bf16_t* Vp  = ws + 3 * SD;
    bf16_t* Wqb = ws + 4 * SD;
    bf16_t* Wkb = Wqb + WW;
    bf16_t* Wvb = Wqb + 2 * WW;
    bf16_t* Wob = Wqb + 3 * WW;
    bf16_t* Vt  = Wqb + 4 * WW;    // (B*H*64, S) transposed V

    dim3 blk(256);
    dim3 gg(8, 64);   // N/128, M/128

    cast4_f32_bf16<<<dim3(1024, 4), blk, 0, stream>>>(Wq, Wk, Wv, Wo, Wqb, Wkb, Wvb, Wob, 262144);

    cast_f32_bf16<<<dim3(8192), blk, 0, stream>>>(q, tmp, 2097152);
    gemm_bt<0><<<gg, blk, 0, stream>>>(tmp, Wqb, Qp);
    cast_f32_bf16<<<dim3(8192), blk, 0, stream>>>(k, tmp, 2097152);
    gemm_bt<0><<<gg, blk, 0, stream>>>(tmp, Wkb, Kp);
    cast_f32_bf16<<<dim3(8192), blk, 0, stream>>>(v, tmp, 2097152);
    gemm_bt<0><<<gg, blk, 0, stream>>>(tmp, Wvb, Vp);

    transpose_v<<<dim3(64, 32), blk, 0, stream>>>(Vp, Vt);
    attn_fused<<<dim3(64, 16), blk, 0, stream>>>(Qp, Kp, Vt, vl, tmp);
    gemm_bt<1><<<gg, blk, 0, stream>>>(tmp, Wob, out);
}

// Round 4
// 365.341 us; speedup vs baseline: 1.3646x; 1.0683x over previous
//
#include <hip/hip_runtime.h>
#include <hip/hip_bf16.h>

using bf16_t = __bf16;
using bf16x8 = __attribute__((ext_vector_type(8))) __bf16;
using bf16x4 = __attribute__((ext_vector_type(4))) __bf16;
using bf16x2 = __attribute__((ext_vector_type(2))) __bf16;
using f32x4  = __attribute__((ext_vector_type(4))) float;

#define S_  2048
#define D_  1024

typedef __attribute__((address_space(1))) unsigned int glb_u32;
typedef __attribute__((address_space(3))) unsigned int lds_u32;

__device__ __forceinline__ void async_cp16(const void* g, void* lds) {
    __builtin_amdgcn_global_load_lds(
        (glb_u32*)(unsigned long long)g,
        (lds_u32*)(unsigned int)(unsigned long long)lds,
        16, 0, 0);
}

// ---------------- f32 -> bf16 casts ----------------
__global__ __launch_bounds__(256) void cast_f32_bf16(const float* __restrict__ s,
                                                     bf16_t* __restrict__ d, int n4) {
    int i = blockIdx.x * 256 + threadIdx.x;
    if (i >= n4) return;
    float4 f = reinterpret_cast<const float4*>(s)[i];
    bf16x4 o;
    o[0] = (bf16_t)f.x; o[1] = (bf16_t)f.y; o[2] = (bf16_t)f.z; o[3] = (bf16_t)f.w;
    reinterpret_cast<bf16x4*>(d)[i] = o;
}

__global__ __launch_bounds__(256) void cast2_f32_bf16(const float* __restrict__ a, const float* __restrict__ b,
                                                      bf16_t* __restrict__ oa, bf16_t* __restrict__ ob, int n4) {
    int i = blockIdx.x * 256 + threadIdx.x;
    if (i >= n4) return;
    const float* s = blockIdx.y ? b : a;
    bf16_t*      d = blockIdx.y ? ob : oa;
    float4 f = reinterpret_cast<const float4*>(s)[i];
    bf16x4 o;
    o[0] = (bf16_t)f.x; o[1] = (bf16_t)f.y; o[2] = (bf16_t)f.z; o[3] = (bf16_t)f.w;
    reinterpret_cast<bf16x4*>(d)[i] = o;
}

__global__ __launch_bounds__(256) void cast4_f32_bf16(const float* __restrict__ a, const float* __restrict__ b,
                                                      const float* __restrict__ c, const float* __restrict__ dd,
                                                      bf16_t* __restrict__ oa, bf16_t* __restrict__ ob,
                                                      bf16_t* __restrict__ oc, bf16_t* __restrict__ od, int n4) {
    int i = blockIdx.x * 256 + threadIdx.x;
    if (i >= n4) return;
    const float* s; bf16_t* d;
    int w = blockIdx.y;
    if      (w == 0) { s = a;  d = oa; }
    else if (w == 1) { s = b;  d = ob; }
    else if (w == 2) { s = c;  d = oc; }
    else             { s = dd; d = od; }
    float4 f = reinterpret_cast<const float4*>(s)[i];
    bf16x4 o;
    o[0] = (bf16_t)f.x; o[1] = (bf16_t)f.y; o[2] = (bf16_t)f.z; o[3] = (bf16_t)f.w;
    reinterpret_cast<bf16x4*>(d)[i] = o;
}

// ---------------- GEMM: C[M x 1024] = A[M x 1024] * Bt[1024 x 1024]^T ----------------
// OUTMODE 0: bf16 row-major (x scale); 1: f32 row-major; 2: bf16 transposed to
//            Vt[((m>>11)*16 + (n>>6))*64 + (n&63)][m&2047]  (per-head V^T layout)
template <int OUTMODE>
__global__ __launch_bounds__(256) void gemm_bt(const bf16_t* __restrict__ A,
                                               const bf16_t* __restrict__ Bt,
                                               void* __restrict__ Cv, float scale) {
    __shared__ bf16_t As[128 * 32];
    __shared__ bf16_t Bs[128 * 32];
    const int K = 1024;
    int tid  = threadIdx.x;
    int lane = tid & 63;
    int w    = tid >> 6;
    int l15  = lane & 15, quad = lane >> 4;
    int m0 = blockIdx.y * 128, n0 = blockIdx.x * 128;
    int wm = (w >> 1) * 64, wn = (w & 1) * 64;

    const bf16_t* Ag = A  + (size_t)(m0 + (tid >> 2)) * K + (tid & 3) * 8;
    const bf16_t* Bg = Bt + (size_t)(n0 + (tid >> 2)) * K + (tid & 3) * 8;
    bf16_t* Asw = As + tid * 8;
    bf16_t* Bsw = Bs + tid * 8;

    f32x4 acc[4][4] = {};

    for (int k0 = 0; k0 < K; k0 += 32) {
        __syncthreads();
        async_cp16(Ag + k0,                    Asw);
        async_cp16(Ag + k0 + (size_t)64 * K,   Asw + 2048);
        async_cp16(Bg + k0,                    Bsw);
        async_cp16(Bg + k0 + (size_t)64 * K,   Bsw + 2048);
        __syncthreads();
        bf16x8 af[4], bfr[4];
#pragma unroll
        for (int t = 0; t < 4; t++) {
            af[t]  = *reinterpret_cast<const bf16x8*>(&As[(wm + t * 16 + l15) * 32 + quad * 8]);
            bfr[t] = *reinterpret_cast<const bf16x8*>(&Bs[(wn + t * 16 + l15) * 32 + quad * 8]);
        }
#pragma unroll
        for (int mt = 0; mt < 4; mt++)
#pragma unroll
            for (int nt = 0; nt < 4; nt++)
                acc[mt][nt] = __builtin_amdgcn_mfma_f32_16x16x32_bf16(af[mt], bfr[nt], acc[mt][nt], 0, 0, 0);
    }

#pragma unroll
    for (int mt = 0; mt < 4; mt++)
#pragma unroll
        for (int nt = 0; nt < 4; nt++) {
            if (OUTMODE == 2) {
                int m = m0 + wm + mt * 16 + quad * 4;   // s-dim base (4 consecutive)
                int n = n0 + wn + nt * 16 + l15;        // d-dim
                bf16x4 o4;
#pragma unroll
                for (int r = 0; r < 4; r++) o4[r] = (bf16_t)(acc[mt][nt][r] * scale);
                size_t vrow = (size_t)((m >> 11) * 16 + (n >> 6)) * 64 + (n & 63);
                *reinterpret_cast<bf16x4*>(&((bf16_t*)Cv)[vrow * S_ + (m & 2047)]) = o4;
            } else {
#pragma unroll
                for (int r = 0; r < 4; r++) {
                    int m = m0 + wm + mt * 16 + quad * 4 + r;
                    int n = n0 + wn + nt * 16 + l15;
                    size_t idx = (size_t)m * 1024 + n;
                    if (OUTMODE == 1) reinterpret_cast<float*>(Cv)[idx] = acc[mt][nt][r] * scale;
                    else              reinterpret_cast<bf16_t*>(Cv)[idx] = (bf16_t)(acc[mt][nt][r] * scale);
                }
            }
        }
}

// ---------------- fused masked attention ----------------
// Transposed-S: St = K Q^T feeds O^T = V^T P^T straight from registers.
// Max-free exp2 softmax; Q pre-scaled by (1/8)log2(e) in its projection GEMM.
// grid (qblk=16, bh=64): co-resident WGs per CU span all 4 batches -> balanced nkb.
__global__ __launch_bounds__(256) void attn_fused(const bf16_t* __restrict__ Qp,
                                                  const bf16_t* __restrict__ Kp,
                                                  const bf16_t* __restrict__ Vt,
                                                  const int* __restrict__ vlen_p,
                                                  bf16_t* __restrict__ Out) {
    __shared__ bf16_t Qs[2 * 128 * 32];   // [kk][row][32]; reused as T[128][64] in epilogue
    __shared__ bf16_t Ks[2 * 64 * 32];    // [kk][row][32]
    __shared__ bf16_t Vs[64 * 68];        // [d][s], stride 68 -> conflict-free b64 reads

    int tid  = threadIdx.x;
    int lane = tid & 63, w = tid >> 6;
    int l15  = lane & 15, quad = lane >> 4;
    int qblk = blockIdx.x;
    int bh = blockIdx.y, b = bh >> 4, h = bh & 15;
    int vlen = vlen_p[b];
    int nkb  = (vlen + 63) >> 6;

    const bf16_t* Qg = Qp + (size_t)(b * S_ + qblk * 128) * D_ + h * 64;
    const bf16_t* Kg = Kp + (size_t)b * S_ * D_ + h * 64;
    const bf16_t* Vg = Vt + (size_t)bh * 64 * S_;

#pragma unroll
    for (int j = 0; j < 4; j++) {
        int linear = j * 256 + tid;
        int kk = linear >> 9, row = (linear >> 2) & 127, sub = linear & 3;
        async_cp16(Qg + (size_t)row * D_ + kk * 32 + sub * 8, Qs + linear * 8);
    }
    __syncthreads();
    bf16x8 qf[2][2];
#pragma unroll
    for (int qt = 0; qt < 2; qt++)
#pragma unroll
        for (int kk = 0; kk < 2; kk++)
            qf[qt][kk] = *reinterpret_cast<const bf16x8*>(&Qs[kk * 4096 + (w * 32 + qt * 16 + l15) * 32 + quad * 8]);

    f32x4 o[2][4] = {};
    float l_st[2] = {0.f, 0.f};

    for (int kb = 0; kb < nkb; kb++) {
        __syncthreads();
#pragma unroll
        for (int j = 0; j < 2; j++) {
            int linear = j * 256 + tid;
            int kk = linear >> 8, row = (linear >> 2) & 63, sub = linear & 3;
            async_cp16(Kg + (size_t)(kb * 64 + row) * D_ + kk * 32 + sub * 8, Ks + linear * 8);
        }
#pragma unroll
        for (int j = 0; j < 2; j++) {
            int linear = j * 256 + tid;
            int row = linear >> 3, c8 = linear & 7;
            uint4 vv = *reinterpret_cast<const uint4*>(&Vg[(size_t)row * S_ + kb * 64 + c8 * 8]);
            uint2* vp = reinterpret_cast<uint2*>(&Vs[row * 68 + c8 * 8]);
            vp[0] = make_uint2(vv.x, vv.y);
            vp[1] = make_uint2(vv.z, vv.w);
        }
        __syncthreads();

        // St = K Q^T, both q-tiles sharing K fragments
        f32x4 sc[2][4] = {};
#pragma unroll
        for (int nt = 0; nt < 4; nt++)
#pragma unroll
            for (int kk = 0; kk < 2; kk++) {
                bf16x8 kf = *reinterpret_cast<const bf16x8*>(&Ks[kk * 2048 + (nt * 16 + l15) * 32 + quad * 8]);
                sc[0][nt] = __builtin_amdgcn_mfma_f32_16x16x32_bf16(kf, qf[0][kk], sc[0][nt], 0, 0, 0);
                sc[1][nt] = __builtin_amdgcn_mfma_f32_16x16x32_bf16(kf, qf[1][kk], sc[1][nt], 0, 0, 0);
            }

        // max-free softmax: p = exp2(st) (scale baked into Q); per-lane l accumulation
        bool partial = (vlen & 63) && (kb == nkb - 1);
        bf16x8 pf[2][2];
        if (!partial) {
#pragma unroll
            for (int qt = 0; qt < 2; qt++) {
                float lacc = 0.f;
#pragma unroll
                for (int nt = 0; nt < 4; nt++)
#pragma unroll
                    for (int r = 0; r < 4; r++) {
                        float p = __builtin_exp2f(sc[qt][nt][r]);
                        lacc += p;
                        pf[qt][nt >> 1][(nt & 1) * 4 + r] = (bf16_t)p;
                    }
                l_st[qt] += lacc;
            }
        } else {
#pragma unroll
            for (int qt = 0; qt < 2; qt++) {
                float lacc = 0.f;
#pragma unroll
                for (int nt = 0; nt < 4; nt++)
#pragma unroll
                    for (int r = 0; r < 4; r++) {
                        float p = __builtin_exp2f(sc[qt][nt][r]);
                        if (kb * 64 + nt * 16 + quad * 4 + r >= vlen) p = 0.f;
                        lacc += p;
                        pf[qt][nt >> 1][(nt & 1) * 4 + r] = (bf16_t)p;
                    }
                l_st[qt] += lacc;
            }
        }

        // O^T += V^T P^T ; V^T A-fragments via conflict-free b64 pairs
#pragma unroll
        for (int np = 0; np < 2; np++)
#pragma unroll
            for (int dt = 0; dt < 4; dt++) {
                bf16x4 v0 = *reinterpret_cast<const bf16x4*>(&Vs[(dt * 16 + l15) * 68 + np * 32 + quad * 4]);
                bf16x4 v1 = *reinterpret_cast<const bf16x4*>(&Vs[(dt * 16 + l15) * 68 + np * 32 + 16 + quad * 4]);
                bf16x8 vf;
#pragma unroll
                for (int j = 0; j < 4; j++) { vf[j] = v0[j]; vf[4 + j] = v1[j]; }
                o[0][dt] = __builtin_amdgcn_mfma_f32_16x16x32_bf16(vf, pf[0][np], o[0][dt], 0, 0, 0);
                o[1][dt] = __builtin_amdgcn_mfma_f32_16x16x32_bf16(vf, pf[1][np], o[1][dt], 0, 0, 0);
            }
    }

    float inv[2];
#pragma unroll
    for (int qt = 0; qt < 2; qt++) {
        float l = l_st[qt];
        l += __shfl_xor(l, 16);
        l += __shfl_xor(l, 32);
        inv[qt] = 1.0f / l;
    }

    // epilogue: O^T -> XOR-swizzled LDS (reuse Qs) -> coalesced row-major store
    __syncthreads();
    bf16_t* T = Qs;
#pragma unroll
    for (int qt = 0; qt < 2; qt++) {
        int row = w * 32 + qt * 16 + l15;
#pragma unroll
        for (int dt = 0; dt < 4; dt++) {
            int phys = ((dt * 2 + (quad >> 1)) ^ (l15 & 7));
            int base = row * 64 + phys * 8 + (quad & 1) * 4;
            bf16x2 t0, t1;
            t0[0] = (bf16_t)(o[qt][dt][0] * inv[qt]);
            t0[1] = (bf16_t)(o[qt][dt][1] * inv[qt]);
            t1[0] = (bf16_t)(o[qt][dt][2] * inv[qt]);
            t1[1] = (bf16_t)(o[qt][dt][3] * inv[qt]);
            *reinterpret_cast<bf16x2*>(&T[base])     = t0;
            *reinterpret_cast<bf16x2*>(&T[base + 2]) = t1;
        }
    }
    __syncthreads();
    {
        int row = w * 32 + (lane >> 1);
        int ch  = lane & 1;
        size_t orow = ((size_t)(b * S_ + qblk * 128) + row) * D_ + h * 64 + ch * 32;
#pragma unroll
        for (int k = 0; k < 4; k++) {
            int phys = (ch * 4 + k) ^ (row & 7);
            bf16x8 frag = *reinterpret_cast<const bf16x8*>(&T[row * 64 + phys * 8]);
            *reinterpret_cast<bf16x8*>(&Out[orow + k * 8]) = frag;
        }
    }
}

extern "C" void kernel_launch(void* const* d_in, const int* in_sizes, int n_in,
                              void* d_out, int out_size, void* d_ws, size_t ws_size,
                              hipStream_t stream) {
    const float* q  = (const float*)d_in[0];
    const float* k  = (const float*)d_in[1];
    const float* v  = (const float*)d_in[2];
    const int*   vl = (const int*)d_in[3];
    const float* Wq = (const float*)d_in[4];
    const float* Wk = (const float*)d_in[5];
    const float* Wv = (const float*)d_in[6];
    const float* Wo = (const float*)d_in[7];
    float* out = (float*)d_out;

    bf16_t* ws = (bf16_t*)d_ws;
    const size_t SD = (size_t)8192 * 1024;
    const size_t WW = (size_t)1024 * 1024;
    bf16_t* tmpA = ws;             // q bf16, then v bf16
    bf16_t* tmpB = ws + SD;        // k bf16, then attn output
    bf16_t* Qp   = ws + 2 * SD;
    bf16_t* Kp   = ws + 3 * SD;
    bf16_t* Vt   = ws + 4 * SD;    // per-head V^T: [(b*16+h)*64+d][s]
    bf16_t* Wqb  = ws + 5 * SD;
    bf16_t* Wkb  = Wqb + WW;
    bf16_t* Wvb  = Wqb + 2 * WW;
    bf16_t* Wob  = Wqb + 3 * WW;
    // total: 5*SD + 4*WW elems = 92.3 MB (same footprint as R3, known-good)

    const float cs = 0.18033688f;  // (1/8)*log2(e) baked into Q projection
    dim3 blk(256);
    dim3 gg(8, 64);

    cast4_f32_bf16<<<dim3(1024, 4), blk, 0, stream>>>(Wq, Wk, Wv, Wo, Wqb, Wkb, Wvb, Wob, 262144);
    cast2_f32_bf16<<<dim3(8192, 2), blk, 0, stream>>>(q, k, tmpA, tmpB, 2097152);

    gemm_bt<0><<<gg, blk, 0, stream>>>(tmpA, Wqb, Qp, cs);
    gemm_bt<0><<<gg, blk, 0, stream>>>(tmpB, Wkb, Kp, 1.0f);
    cast_f32_bf16<<<dim3(8192), blk, 0, stream>>>(v, tmpA, 2097152);
    gemm_bt<2><<<gg, blk, 0, stream>>>(tmpA, Wvb, Vt, 1.0f);

    attn_fused<<<dim3(16, 64), blk, 0, stream>>>(Qp, Kp, Vt, vl, tmpB);
    gemm_bt<1><<<gg, blk, 0, stream>>>(tmpB, Wob, out, 1.0f);
}